// Round 1
// baseline (428.905 us; speedup 1.0000x reference)
//
#include <hip/hip_runtime.h>
#include <hip/hip_bf16.h>

#define EPS 1e-5f

typedef __attribute__((ext_vector_type(8))) short short8;
typedef __attribute__((ext_vector_type(4))) short short4v;
typedef __attribute__((ext_vector_type(4))) float floatx4;

__device__ inline float b2f(short s) {
    union { unsigned u; float f; } v;
    v.u = ((unsigned)(unsigned short)s) << 16;
    return v.f;
}
__device__ inline float sigmoidf_(float x) { return 1.f / (1.f + __expf(-x)); }
__device__ inline float tanhf_(float x) { return 1.f - 2.f / (__expf(2.f * x) + 1.f); }

// ---------------------------------------------------------------------------
// GEMM: out[m][n] = bf16( sum_k A[m][k]*W[n][k] + bias[n] )
// A: [8192 x K] fp32 row-major, W: [4096 x K] fp32 row-major, out: [8192 x 4096] bf16
// Tile 128x128, BK=64, 256 threads = 4 waves in 2x2, each wave 64x64 via 4x4
// mfma_f32_16x16x32_bf16 tiles. fp32->bf16 conversion happens during staging.
// LDS row stride 88 bf16 (176 B): 16B-aligned for b128, 2-way bank alias (free).
// ---------------------------------------------------------------------------
#define LDT 88

__global__ __launch_bounds__(256, 2)
void gemm_bias(const float* __restrict__ A, const float* __restrict__ W,
               const float* __restrict__ bias, __hip_bfloat16* __restrict__ out,
               int K) {
    __shared__ alignas(16) __hip_bfloat16 sA[128 * LDT];
    __shared__ alignas(16) __hip_bfloat16 sB[128 * LDT];

    const int t    = threadIdx.x;
    const int bn   = blockIdx.x;     // 32
    const int bm   = blockIdx.y;     // 64
    const int m0   = bm * 128;
    const int n0   = bn * 128;

    const int lane = t & 63;
    const int wave = t >> 6;
    const int quad = lane >> 4;
    const int rl   = lane & 15;
    const int wm   = (wave >> 1) * 64;
    const int wn   = (wave & 1) * 64;

    floatx4 acc[4][4];
    #pragma unroll
    for (int i = 0; i < 4; ++i)
        #pragma unroll
        for (int j = 0; j < 4; ++j)
            acc[i][j] = (floatx4){0.f, 0.f, 0.f, 0.f};

    const int seg = t & 7;   // 8-float column group within BK=64
    const int rw  = t >> 3;  // 0..31

    for (int k0 = 0; k0 < K; k0 += 64) {
        __syncthreads();
        #pragma unroll
        for (int it = 0; it < 4; ++it) {
            const int row = it * 32 + rw;
            {
                const float4* ap = (const float4*)(A + (size_t)(m0 + row) * K + k0 + seg * 8);
                float4 v0 = ap[0], v1 = ap[1];
                union { short8 s; __hip_bfloat16 h[8]; } u;
                u.h[0] = __float2bfloat16(v0.x); u.h[1] = __float2bfloat16(v0.y);
                u.h[2] = __float2bfloat16(v0.z); u.h[3] = __float2bfloat16(v0.w);
                u.h[4] = __float2bfloat16(v1.x); u.h[5] = __float2bfloat16(v1.y);
                u.h[6] = __float2bfloat16(v1.z); u.h[7] = __float2bfloat16(v1.w);
                *(short8*)(sA + row * LDT + seg * 8) = u.s;
            }
            {
                const float4* wp = (const float4*)(W + (size_t)(n0 + row) * K + k0 + seg * 8);
                float4 v0 = wp[0], v1 = wp[1];
                union { short8 s; __hip_bfloat16 h[8]; } u;
                u.h[0] = __float2bfloat16(v0.x); u.h[1] = __float2bfloat16(v0.y);
                u.h[2] = __float2bfloat16(v0.z); u.h[3] = __float2bfloat16(v0.w);
                u.h[4] = __float2bfloat16(v1.x); u.h[5] = __float2bfloat16(v1.y);
                u.h[6] = __float2bfloat16(v1.z); u.h[7] = __float2bfloat16(v1.w);
                *(short8*)(sB + row * LDT + seg * 8) = u.s;
            }
        }
        __syncthreads();
        #pragma unroll
        for (int kk = 0; kk < 64; kk += 32) {
            short8 aF[4], bF[4];
            #pragma unroll
            for (int i = 0; i < 4; ++i)
                aF[i] = *(const short8*)(sA + (wm + i * 16 + rl) * LDT + kk + quad * 8);
            #pragma unroll
            for (int j = 0; j < 4; ++j)
                bF[j] = *(const short8*)(sB + (wn + j * 16 + rl) * LDT + kk + quad * 8);
            #pragma unroll
            for (int i = 0; i < 4; ++i)
                #pragma unroll
                for (int j = 0; j < 4; ++j)
                    acc[i][j] = __builtin_amdgcn_mfma_f32_16x16x32_bf16(aF[i], bF[j], acc[i][j], 0, 0, 0);
        }
    }

    // Epilogue: + bias, store bf16. C/D layout: col=lane&15, row=quad*4+reg.
    #pragma unroll
    for (int j = 0; j < 4; ++j) {
        const int n = n0 + wn + j * 16 + rl;
        const float bv = bias[n];
        #pragma unroll
        for (int i = 0; i < 4; ++i) {
            const int mrow = m0 + wm + i * 16 + quad * 4;
            #pragma unroll
            for (int r = 0; r < 4; ++r)
                out[(size_t)(mrow + r) * 4096 + n] = __float2bfloat16(acc[i][j][r] + bv);
        }
    }
}

// ---------------------------------------------------------------------------
// Fused: LN(Pi)+LN(Ph) -> gates -> c_new -> LN(c_new) -> h_new
// One block (256 thr) per row.
// ---------------------------------------------------------------------------
__device__ inline void red4(float& a, float& b, float& c, float& d, float* sred) {
    #pragma unroll
    for (int off = 32; off > 0; off >>= 1) {
        a += __shfl_down(a, off); b += __shfl_down(b, off);
        c += __shfl_down(c, off); d += __shfl_down(d, off);
    }
    const int w = threadIdx.x >> 6;
    if ((threadIdx.x & 63) == 0) {
        sred[w] = a; sred[w + 4] = b; sred[w + 8] = c; sred[w + 12] = d;
    }
    __syncthreads();
    a = sred[0] + sred[1] + sred[2] + sred[3];
    b = sred[4] + sred[5] + sred[6] + sred[7];
    c = sred[8] + sred[9] + sred[10] + sred[11];
    d = sred[12] + sred[13] + sred[14] + sred[15];
    __syncthreads();
}

__device__ inline void red2(float& a, float& b, float* sred) {
    #pragma unroll
    for (int off = 32; off > 0; off >>= 1) {
        a += __shfl_down(a, off); b += __shfl_down(b, off);
    }
    const int w = threadIdx.x >> 6;
    if ((threadIdx.x & 63) == 0) { sred[w] = a; sred[w + 4] = b; }
    __syncthreads();
    a = sred[0] + sred[1] + sred[2] + sred[3];
    b = sred[4] + sred[5] + sred[6] + sred[7];
    __syncthreads();
}

__global__ __launch_bounds__(256)
void ln_gates(const __hip_bfloat16* __restrict__ Pi, const __hip_bfloat16* __restrict__ Ph,
              const float* __restrict__ c_prev,
              const float* __restrict__ g_in, const float* __restrict__ b_in,
              const float* __restrict__ g_hid, const float* __restrict__ b_hid,
              const float* __restrict__ g_cell, const float* __restrict__ b_cell,
              float* __restrict__ h_out, float* __restrict__ c_out) {
    const int row = blockIdx.x;
    const int t   = threadIdx.x;
    __shared__ float sred[16];

    const __hip_bfloat16* pi = Pi + (size_t)row * 4096;
    const __hip_bfloat16* ph = Ph + (size_t)row * 4096;

    // Phase A: mean/var of both projections over 4096
    float si = 0.f, sqi = 0.f, sh = 0.f, sqh = 0.f;
    #pragma unroll
    for (int it = 0; it < 2; ++it) {
        const int s = t + it * 256;
        short8 vi = *(const short8*)(pi + s * 8);
        short8 vh = *(const short8*)(ph + s * 8);
        #pragma unroll
        for (int e = 0; e < 8; ++e) {
            float f = b2f(vi[e]); si += f; sqi += f * f;
            float g = b2f(vh[e]); sh += g; sqh += g * g;
        }
    }
    red4(si, sqi, sh, sqh, sred);
    const float mu_i = si * (1.f / 4096.f);
    const float rs_i = rsqrtf(sqi * (1.f / 4096.f) - mu_i * mu_i + EPS);
    const float mu_h = sh * (1.f / 4096.f);
    const float rs_h = rsqrtf(sqh * (1.f / 4096.f) - mu_h * mu_h + EPS);

    // Phase B: gates + c_new, each thread handles 4 consecutive j
    const int j0 = t * 4;
    float comb[4][4];
    #pragma unroll
    for (int gidx = 0; gidx < 4; ++gidx) {
        const int col = gidx * 1024 + j0;
        short4v vi = *(const short4v*)(pi + col);
        short4v vh = *(const short4v*)(ph + col);
        floatx4 gi  = *(const floatx4*)(g_in  + col);
        floatx4 bii = *(const floatx4*)(b_in  + col);
        floatx4 gh  = *(const floatx4*)(g_hid + col);
        floatx4 bhh = *(const floatx4*)(b_hid + col);
        #pragma unroll
        for (int e = 0; e < 4; ++e)
            comb[gidx][e] = (b2f(vi[e]) - mu_i) * rs_i * gi[e] + bii[e]
                          + (b2f(vh[e]) - mu_h) * rs_h * gh[e] + bhh[e];
    }

    floatx4 cp = *(const floatx4*)(c_prev + (size_t)row * 1024 + j0);
    float cn[4], ov[4];
    float sc = 0.f, scq = 0.f;
    #pragma unroll
    for (int e = 0; e < 4; ++e) {
        const float iv = sigmoidf_(comb[0][e]);
        const float fv = sigmoidf_(comb[1][e]);
        const float gv = tanhf_(comb[2][e]);
        ov[e] = sigmoidf_(comb[3][e]);
        const float c = fv * cp[e] + iv * gv;
        cn[e] = c; sc += c; scq += c * c;
    }
    red2(sc, scq, sred);
    const float mu_c = sc * (1.f / 1024.f);
    const float rs_c = rsqrtf(scq * (1.f / 1024.f) - mu_c * mu_c + EPS);

    floatx4 gc = *(const floatx4*)(g_cell + j0);
    floatx4 bc = *(const floatx4*)(b_cell + j0);
    floatx4 hv, cv;
    #pragma unroll
    for (int e = 0; e < 4; ++e) {
        const float nc = (cn[e] - mu_c) * rs_c * gc[e] + bc[e];
        hv[e] = ov[e] * tanhf_(nc);
        cv[e] = cn[e];
    }
    *(floatx4*)(h_out + (size_t)row * 1024 + j0) = hv;
    *(floatx4*)(c_out + (size_t)row * 1024 + j0) = cv;
}

// ---------------------------------------------------------------------------
extern "C" void kernel_launch(void* const* d_in, const int* in_sizes, int n_in,
                              void* d_out, int out_size, void* d_ws, size_t ws_size,
                              hipStream_t stream) {
    const float* x      = (const float*)d_in[0];
    const float* h_prev = (const float*)d_in[1];
    const float* c_prev = (const float*)d_in[2];
    const float* Wi     = (const float*)d_in[3];
    const float* bi     = (const float*)d_in[4];
    const float* Wh     = (const float*)d_in[5];
    const float* bh     = (const float*)d_in[6];
    const float* g_in   = (const float*)d_in[7];
    const float* b_in   = (const float*)d_in[8];
    const float* g_hid  = (const float*)d_in[9];
    const float* b_hid  = (const float*)d_in[10];
    const float* g_cell = (const float*)d_in[11];
    const float* b_cell = (const float*)d_in[12];

    __hip_bfloat16* Pi = (__hip_bfloat16*)d_ws;                 // 8192*4096 bf16 = 64 MiB
    __hip_bfloat16* Ph = Pi + (size_t)8192 * 4096;              // 64 MiB more

    float* h_out = (float*)d_out;
    float* c_out = h_out + (size_t)8192 * 1024;

    dim3 grid(32, 64), blk(256);
    hipLaunchKernelGGL(gemm_bias, grid, blk, 0, stream, x, Wi, bi, Pi, 512);
    hipLaunchKernelGGL(gemm_bias, grid, blk, 0, stream, h_prev, Wh, bh, Ph, 1024);
    hipLaunchKernelGGL(ln_gates, dim3(8192), blk, 0, stream, Pi, Ph, c_prev,
                       g_in, b_in, g_hid, b_hid, g_cell, b_cell, h_out, c_out);
}

// Round 2
// 340.583 us; speedup vs baseline: 1.2593x; 1.2593x over previous
//
#include <hip/hip_runtime.h>
#include <hip/hip_bf16.h>

#define EPS 1e-5f

typedef __attribute__((ext_vector_type(8))) short short8;
typedef __attribute__((ext_vector_type(4))) short short4v;
typedef __attribute__((ext_vector_type(4))) float floatx4;

__device__ inline float b2f(short s) {
    union { unsigned u; float f; } v;
    v.u = ((unsigned)(unsigned short)s) << 16;
    return v.f;
}
__device__ inline float sigmoidf_(float x) { return 1.f / (1.f + __expf(-x)); }
__device__ inline float tanhf_(float x) { return 1.f - 2.f / (__expf(2.f * x) + 1.f); }

__device__ inline void load_lds16(const void* g, void* l) {
    __builtin_amdgcn_global_load_lds(
        (const __attribute__((address_space(1))) void*)g,
        (__attribute__((address_space(3))) void*)l, 16, 0, 0);
}

// ---------------------------------------------------------------------------
// fp32 -> bf16 converts for x, h_prev, Wi, Wh (blockIdx.y selects segment)
// ---------------------------------------------------------------------------
__global__ __launch_bounds__(256)
void cvt_bf16(const float* __restrict__ s0, __hip_bfloat16* __restrict__ d0, int n0_,
              const float* __restrict__ s1, __hip_bfloat16* __restrict__ d1, int n1_,
              const float* __restrict__ s2, __hip_bfloat16* __restrict__ d2, int n2_,
              const float* __restrict__ s3, __hip_bfloat16* __restrict__ d3, int n3_) {
    const float* s; __hip_bfloat16* d; int n;
    switch (blockIdx.y) {
        case 0:  s = s0; d = d0; n = n0_; break;
        case 1:  s = s1; d = d1; n = n1_; break;
        case 2:  s = s2; d = d2; n = n2_; break;
        default: s = s3; d = d3; n = n3_; break;
    }
    const int idx = (blockIdx.x * 256 + threadIdx.x) * 4;
    if (idx < n) {
        float4 v = *(const float4*)(s + idx);
        union { short4v sv; __hip_bfloat16 h[4]; } u;
        u.h[0] = __float2bfloat16(v.x); u.h[1] = __float2bfloat16(v.y);
        u.h[2] = __float2bfloat16(v.z); u.h[3] = __float2bfloat16(v.w);
        *(short4v*)(d + idx) = u.sv;
    }
}

// ---------------------------------------------------------------------------
// GEMM: out[m][n] = bf16( sum_k A[m][k]*W[n][k] + bias[n] )
// A: [8192 x K] bf16, W: [4096 x K] bf16, out: [8192 x 4096] bf16
// 128x128 tile, BK=64, 4 waves (2x2), 4x4 mfma_f32_16x16x32_bf16 per wave.
// Staging: global_load_lds width=16, XOR-swizzled chunk layout (no padding
// allowed with load-lds; swizzle breaks same-bank row stride).
// Epilogue: acc+bias -> padded LDS (stride 136) -> coalesced 16B stores.
// ---------------------------------------------------------------------------
__global__ __launch_bounds__(256, 3)
void gemm_bf16(const __hip_bfloat16* __restrict__ A, const __hip_bfloat16* __restrict__ W,
               const float* __restrict__ bias, __hip_bfloat16* __restrict__ out, int K) {
    __shared__ alignas(16) __hip_bfloat16 smem[17408]; // >= 2*8192 staging, 128*136 epilogue
    __hip_bfloat16* sA = smem;          // 128x64 bf16 = 8192 elem (1024 16B-chunks)
    __hip_bfloat16* sB = smem + 8192;

    const int t    = threadIdx.x;
    const int lane = t & 63;
    const int wave = t >> 6;
    const int quad = lane >> 4;
    const int rl   = lane & 15;
    const int wm   = (wave >> 1) * 64;
    const int wn   = (wave & 1) * 64;
    const int m0   = blockIdx.y * 128;
    const int n0   = blockIdx.x * 128;

    floatx4 acc[4][4];
    #pragma unroll
    for (int i = 0; i < 4; ++i)
        #pragma unroll
        for (int j = 0; j < 4; ++j)
            acc[i][j] = (floatx4){0.f, 0.f, 0.f, 0.f};

    // staging mapping: linear chunk cl = (wave*4+i)*64 + lane
    // row = cl>>3, slot = cl&7, global k-chunk c8 = slot ^ (row&7)
    int srow[4], scol[4];
    #pragma unroll
    for (int i = 0; i < 4; ++i) {
        const int cl  = (wave * 4 + i) * 64 + lane;
        const int row = cl >> 3;
        srow[i] = row;
        scol[i] = ((cl & 7) ^ (row & 7)) * 8;
    }

    for (int k0 = 0; k0 < K; k0 += 64) {
        __syncthreads();
        #pragma unroll
        for (int i = 0; i < 4; ++i) {
            load_lds16(A + (size_t)(m0 + srow[i]) * K + k0 + scol[i], sA + (wave * 4 + i) * 512);
            load_lds16(W + (size_t)(n0 + srow[i]) * K + k0 + scol[i], sB + (wave * 4 + i) * 512);
        }
        __syncthreads();
        #pragma unroll
        for (int kk = 0; kk < 2; ++kk) {
            short8 aF[4], bF[4];
            #pragma unroll
            for (int i = 0; i < 4; ++i) {
                const int r = wm + i * 16 + rl;
                const int c = kk * 4 + quad;
                aF[i] = *(const short8*)(sA + (r * 8 + (c ^ (r & 7))) * 8);
            }
            #pragma unroll
            for (int j = 0; j < 4; ++j) {
                const int r = wn + j * 16 + rl;
                const int c = kk * 4 + quad;
                bF[j] = *(const short8*)(sB + (r * 8 + (c ^ (r & 7))) * 8);
            }
            #pragma unroll
            for (int i = 0; i < 4; ++i)
                #pragma unroll
                for (int j = 0; j < 4; ++j)
                    acc[i][j] = __builtin_amdgcn_mfma_f32_16x16x32_bf16(aF[i], bF[j], acc[i][j], 0, 0, 0);
        }
    }

    __syncthreads();
    // epilogue: bias + cvt into padded LDS. C/D layout: col=lane&15, row=quad*4+reg.
    #pragma unroll
    for (int j = 0; j < 4; ++j) {
        const int col = wn + j * 16 + rl;
        const float bv = bias[n0 + col];
        #pragma unroll
        for (int i = 0; i < 4; ++i) {
            const int rbase = wm + i * 16 + quad * 4;
            #pragma unroll
            for (int r = 0; r < 4; ++r)
                smem[(rbase + r) * 136 + col] = __float2bfloat16(acc[i][j][r] + bv);
        }
    }
    __syncthreads();
    #pragma unroll
    for (int p = 0; p < 8; ++p) {
        const int ch  = p * 256 + t;
        const int row = ch >> 4;
        const int c8  = (ch & 15) * 8;
        short8 v = *(const short8*)(smem + row * 136 + c8);
        *(short8*)(out + (size_t)(m0 + row) * 4096 + n0 + c8) = v;
    }
}

// ---------------------------------------------------------------------------
// Fused: LN(Pi)+LN(Ph) -> gates -> c_new -> LN(c_new) -> h_new
// ---------------------------------------------------------------------------
__device__ inline void red4(float& a, float& b, float& c, float& d, float* sred) {
    #pragma unroll
    for (int off = 32; off > 0; off >>= 1) {
        a += __shfl_down(a, off); b += __shfl_down(b, off);
        c += __shfl_down(c, off); d += __shfl_down(d, off);
    }
    const int w = threadIdx.x >> 6;
    if ((threadIdx.x & 63) == 0) {
        sred[w] = a; sred[w + 4] = b; sred[w + 8] = c; sred[w + 12] = d;
    }
    __syncthreads();
    a = sred[0] + sred[1] + sred[2] + sred[3];
    b = sred[4] + sred[5] + sred[6] + sred[7];
    c = sred[8] + sred[9] + sred[10] + sred[11];
    d = sred[12] + sred[13] + sred[14] + sred[15];
    __syncthreads();
}

__device__ inline void red2(float& a, float& b, float* sred) {
    #pragma unroll
    for (int off = 32; off > 0; off >>= 1) {
        a += __shfl_down(a, off); b += __shfl_down(b, off);
    }
    const int w = threadIdx.x >> 6;
    if ((threadIdx.x & 63) == 0) { sred[w] = a; sred[w + 4] = b; }
    __syncthreads();
    a = sred[0] + sred[1] + sred[2] + sred[3];
    b = sred[4] + sred[5] + sred[6] + sred[7];
    __syncthreads();
}

__global__ __launch_bounds__(256)
void ln_gates(const __hip_bfloat16* __restrict__ Pi, const __hip_bfloat16* __restrict__ Ph,
              const float* __restrict__ c_prev,
              const float* __restrict__ g_in, const float* __restrict__ b_in,
              const float* __restrict__ g_hid, const float* __restrict__ b_hid,
              const float* __restrict__ g_cell, const float* __restrict__ b_cell,
              float* __restrict__ h_out, float* __restrict__ c_out) {
    const int row = blockIdx.x;
    const int t   = threadIdx.x;
    __shared__ float sred[16];

    const __hip_bfloat16* pi = Pi + (size_t)row * 4096;
    const __hip_bfloat16* ph = Ph + (size_t)row * 4096;

    float si = 0.f, sqi = 0.f, sh = 0.f, sqh = 0.f;
    #pragma unroll
    for (int it = 0; it < 2; ++it) {
        const int s = t + it * 256;
        short8 vi = *(const short8*)(pi + s * 8);
        short8 vh = *(const short8*)(ph + s * 8);
        #pragma unroll
        for (int e = 0; e < 8; ++e) {
            float f = b2f(vi[e]); si += f; sqi += f * f;
            float g = b2f(vh[e]); sh += g; sqh += g * g;
        }
    }
    red4(si, sqi, sh, sqh, sred);
    const float mu_i = si * (1.f / 4096.f);
    const float rs_i = rsqrtf(sqi * (1.f / 4096.f) - mu_i * mu_i + EPS);
    const float mu_h = sh * (1.f / 4096.f);
    const float rs_h = rsqrtf(sqh * (1.f / 4096.f) - mu_h * mu_h + EPS);

    const int j0 = t * 4;
    float comb[4][4];
    #pragma unroll
    for (int gidx = 0; gidx < 4; ++gidx) {
        const int col = gidx * 1024 + j0;
        short4v vi = *(const short4v*)(pi + col);
        short4v vh = *(const short4v*)(ph + col);
        floatx4 gi  = *(const floatx4*)(g_in  + col);
        floatx4 bii = *(const floatx4*)(b_in  + col);
        floatx4 gh  = *(const floatx4*)(g_hid + col);
        floatx4 bhh = *(const floatx4*)(b_hid + col);
        #pragma unroll
        for (int e = 0; e < 4; ++e)
            comb[gidx][e] = (b2f(vi[e]) - mu_i) * rs_i * gi[e] + bii[e]
                          + (b2f(vh[e]) - mu_h) * rs_h * gh[e] + bhh[e];
    }

    floatx4 cp = *(const floatx4*)(c_prev + (size_t)row * 1024 + j0);
    float cn[4], ov[4];
    float sc = 0.f, scq = 0.f;
    #pragma unroll
    for (int e = 0; e < 4; ++e) {
        const float iv = sigmoidf_(comb[0][e]);
        const float fv = sigmoidf_(comb[1][e]);
        const float gv = tanhf_(comb[2][e]);
        ov[e] = sigmoidf_(comb[3][e]);
        const float c = fv * cp[e] + iv * gv;
        cn[e] = c; sc += c; scq += c * c;
    }
    red2(sc, scq, sred);
    const float mu_c = sc * (1.f / 1024.f);
    const float rs_c = rsqrtf(scq * (1.f / 1024.f) - mu_c * mu_c + EPS);

    floatx4 gc = *(const floatx4*)(g_cell + j0);
    floatx4 bc = *(const floatx4*)(b_cell + j0);
    floatx4 hv, cv;
    #pragma unroll
    for (int e = 0; e < 4; ++e) {
        const float nc = (cn[e] - mu_c) * rs_c * gc[e] + bc[e];
        hv[e] = ov[e] * tanhf_(nc);
        cv[e] = cn[e];
    }
    *(floatx4*)(h_out + (size_t)row * 1024 + j0) = hv;
    *(floatx4*)(c_out + (size_t)row * 1024 + j0) = cv;
}

// ---------------------------------------------------------------------------
extern "C" void kernel_launch(void* const* d_in, const int* in_sizes, int n_in,
                              void* d_out, int out_size, void* d_ws, size_t ws_size,
                              hipStream_t stream) {
    const float* x      = (const float*)d_in[0];
    const float* h_prev = (const float*)d_in[1];
    const float* c_prev = (const float*)d_in[2];
    const float* Wi     = (const float*)d_in[3];
    const float* bi     = (const float*)d_in[4];
    const float* Wh     = (const float*)d_in[5];
    const float* bh     = (const float*)d_in[6];
    const float* g_in   = (const float*)d_in[7];
    const float* b_in   = (const float*)d_in[8];
    const float* g_hid  = (const float*)d_in[9];
    const float* b_hid  = (const float*)d_in[10];
    const float* g_cell = (const float*)d_in[11];
    const float* b_cell = (const float*)d_in[12];

    // ws: Pi (64 MiB) + Ph (64 MiB)
    __hip_bfloat16* Pi = (__hip_bfloat16*)d_ws;
    __hip_bfloat16* Ph = Pi + (size_t)8192 * 4096;

    // d_out doubles as scratch for bf16-converted inputs; ln_gates fully
    // overwrites all 64 MiB of d_out at the end of every call.
    const int NX = 8192 * 512, NH = 8192 * 1024, NWI = 4096 * 512, NWH = 4096 * 1024;
    __hip_bfloat16* xb  = (__hip_bfloat16*)d_out;
    __hip_bfloat16* hb  = xb + NX;
    __hip_bfloat16* Wib = hb + NH;
    __hip_bfloat16* Whb = Wib + NWI;

    float* h_out = (float*)d_out;
    float* c_out = h_out + (size_t)8192 * 1024;

    hipLaunchKernelGGL(cvt_bf16, dim3(8192, 4), dim3(256), 0, stream,
                       x, xb, NX, h_prev, hb, NH, Wi, Wib, NWI, Wh, Whb, NWH);

    dim3 grid(32, 64), blk(256);
    hipLaunchKernelGGL(gemm_bf16, grid, blk, 0, stream, xb, Wib, bi, Pi, 512);
    hipLaunchKernelGGL(gemm_bf16, grid, blk, 0, stream, hb, Whb, bh, Ph, 1024);
    hipLaunchKernelGGL(ln_gates, dim3(8192), blk, 0, stream, Pi, Ph, c_prev,
                       g_in, b_in, g_hid, b_hid, g_cell, b_cell, h_out, c_out);
}